// Round 5
// baseline (204.782 us; speedup 1.0000x reference)
//
#include <hip/hip_runtime.h>
#include <hip/hip_bf16.h>

typedef float f32x4 __attribute__((ext_vector_type(4)));
typedef short s16x8 __attribute__((ext_vector_type(8)));

#define NPIX       12544      // B*nH*nW = 16*28*28
#define OUT_STRIDE 12845056   // 16*112*112*64 elements per stream output
#define NTILES     1568       // 784 pixel-groups x 2 streams
#define GRIDX      512        // 2 blocks/CU

__device__ __forceinline__ unsigned short f2bf(float x) {
    union { float f; unsigned u; } un; un.f = x;
    unsigned r = un.u + 0x7FFFu + ((un.u >> 16) & 1u);  // RNE
    return (unsigned short)(r >> 16);
}

__device__ __forceinline__ short bfs(float x) {
    __hip_bfloat16 h = __float2bfloat16(x);
    return *reinterpret_cast<short*>(&h);
}

__device__ __forceinline__ void gload_lds16(const void* g, void* l) {
    __builtin_amdgcn_global_load_lds(
        (const __attribute__((address_space(1))) unsigned int*)g,
        (__attribute__((address_space(3))) unsigned int*)l, 16, 0, 0);
}

// Repack weights fp32 -> bf16 MFMA B-fragments in d_ws, scaled by 1/16.
// Fragment (lane,e) = w[t][c = ks*32 + (lane>>4)*8 + e][k = nt*16 + (lane&15)] / 16
// at granule (((s*16+t)*2+ks)*4+nt)*64+lane, element e.
__global__ __launch_bounds__(256) void repack_weights(
        const float* __restrict__ w1, const float* __restrict__ w2,
        unsigned short* __restrict__ wf) {
    int gid = blockIdx.x * 256 + threadIdx.x;   // [s][t][c][k], k fastest
    int k = gid & 63;
    int c = (gid >> 6) & 63;
    int t = (gid >> 12) & 15;
    int s = (gid >> 16) & 1;
    const float* __restrict__ w = s ? w2 : w1;
    float val = w[gid & 65535] * 0.0625f;
    int e = c & 7, lhi = (c >> 3) & 3, ks = c >> 5;
    int l  = lhi * 16 + (k & 15);
    int nt = k >> 4;
    int dst = ((((s * 16 + t) * 2 + ks) * 4 + nt) * 64 + l) * 8 + e;
    wf[dst] = f2bf(val);
}

// Persistent 2-phase pipeline over half-tiles (8 t-planes = 32 KB fp32).
// Counted vmcnt + raw barriers: stage(m+1) stays in flight across compute(m);
// stores are never drained inside the loop.
__global__ __launch_bounds__(256, 2) void iwht_main(
        const float* __restrict__ trans1, const float* __restrict__ trans2,
        const unsigned short* __restrict__ wf,
        const float* __restrict__ bias1, const float* __restrict__ bias2,
        float* __restrict__ out) {
    __shared__ __align__(16) unsigned char lds[65536];   // 2 x 32 KB half-buffers

    const int tid  = threadIdx.x;
    const int wid  = tid >> 6;
    const int lane = tid & 63;
    const int lrow = lane & 15;
    const int lhi  = lane >> 4;
    const int bx   = blockIdx.x;

    const int   kk  = wid * 16 + lrow;   // this wave's k (C/D col = lane&15)
    const float bk1 = bias1[kk];
    const float bk2 = bias2[kk];

    const int M = ((NTILES - bx + GRIDX - 1) / GRIDX) * 2;   // 6 or 8 halves

    // staging: wave wid stages granule q=wid; per-lane pre-swizzled global source
    const int qsrc = (wid >> 1) * 32 + lhi * 8 + (wid & 1) * 4;
    const s16x8* __restrict__ wbbase = (const s16x8*)wf + (size_t)wid * 64 + lane;

    // issue the 8 gl_lds for half m into buf[m&1]
    auto stage_half = [&](int m) {
        const int tau = bx + (m >> 1) * GRIDX;
        const int hf  = m & 1;
        const int s   = (tau >= 784) ? 1 : 0;
        const int bid = tau - s * 784;
        const float* __restrict__ tr = s ? trans2 : trans1;
        const float* g0 = tr + (size_t)(bid * 16 + lrow) * 64 + qsrc;
        unsigned char* db = lds + (m & 1) * 32768 + wid * 1024;
        #pragma unroll
        for (int tt = 0; tt < 8; ++tt) {
            const int t = hf * 8 + tt;
            gload_lds16(g0 + (size_t)t * (NPIX * 64), db + tt * 4096);
        }
    };

    f32x4 o[4][4];
    #pragma unroll
    for (int i = 0; i < 4; ++i)
        #pragma unroll
        for (int j = 0; j < 4; ++j)
            o[i][j] = (f32x4){0.f, 0.f, 0.f, 0.f};

    s16x8 bH[16];   // B fragments for current half: [tt*2 + ks], statically indexed

    stage_half(0);

    #pragma unroll 1
    for (int m = 0; m < M; ++m) {
        const int tau = bx + (m >> 1) * GRIDX;
        const int hf  = m & 1;
        const int s   = (tau >= 784) ? 1 : 0;
        const int bid = tau - s * 784;

        // ---- B fragments for half m (L2-resident, hidden under vmcnt wait) ----
        {
            const s16x8* __restrict__ wb = wbbase + (size_t)s * 8192;
            #pragma unroll
            for (int tt = 0; tt < 8; ++tt) {
                const int t = hf * 8 + tt;
                bH[tt * 2 + 0] = wb[(size_t)(t * 2 + 0) * 256];
                bH[tt * 2 + 1] = wb[(size_t)(t * 2 + 1) * 256];
            }
        }

        // ---- issue next half's staging BEFORE waiting ----
        if (m + 1 < M) {
            stage_half(m + 1);
            asm volatile("s_waitcnt vmcnt(8)" ::: "memory");   // half m + B landed; m+1 in flight
        } else {
            asm volatile("s_waitcnt vmcnt(0)" ::: "memory");
        }
        __builtin_amdgcn_sched_barrier(0);
        __builtin_amdgcn_s_barrier();      // raw: no store drain

        // ---- compute half m: u-groups {hf*2, hf*2+1} ----
        const unsigned char* __restrict__ hb = lds + (m & 1) * 32768;
        #pragma unroll
        for (int g = 0; g < 2; ++g) {
            f32x4 acc[4];
            #pragma unroll
            for (int v = 0; v < 4; ++v) {
                const int tt = g * 4 + v;
                const unsigned char* ab = hb + tt * 4096 + lane * 16;
                f32x4 q0 = *(const f32x4*)(ab);
                f32x4 q1 = *(const f32x4*)(ab + 1024);
                f32x4 q2 = *(const f32x4*)(ab + 2048);
                f32x4 q3 = *(const f32x4*)(ab + 3072);
                s16x8 a0, a1;
                #pragma unroll
                for (int e = 0; e < 4; ++e) {
                    a0[e] = bfs(q0[e]); a0[4 + e] = bfs(q1[e]);
                    a1[e] = bfs(q2[e]); a1[4 + e] = bfs(q3[e]);
                }
                f32x4 tacc = {0.f, 0.f, 0.f, 0.f};
                tacc = __builtin_amdgcn_mfma_f32_16x16x32_bf16(a0, bH[tt * 2 + 0], tacc, 0, 0, 0);
                tacc = __builtin_amdgcn_mfma_f32_16x16x32_bf16(a1, bH[tt * 2 + 1], tacc, 0, 0, 0);
                acc[v] = tacc;
            }
            // v-butterfly
            f32x4 e0 = acc[0] + acc[1], e1 = acc[0] - acc[1];
            f32x4 e2 = acc[2] + acc[3], e3 = acc[2] - acc[3];
            f32x4 g0 = e0 + e2, g1 = e1 + e3, g2 = e0 - e2, g3 = e1 - e3;
            const int u = hf * 2 + g;
            const float s1 = (u & 1) ? -1.f : 1.f;
            const float s2 = (u & 2) ? -1.f : 1.f;
            const float s3 = s1 * s2;
            #pragma unroll
            for (int j = 0; j < 4; ++j) {
                f32x4 gj = (j == 0) ? g0 : ((j == 1) ? g1 : ((j == 2) ? g2 : g3));
                o[0][j] += gj;
                o[1][j] += s1 * gj;
                o[2][j] += s2 * gj;
                o[3][j] += s3 * gj;
            }
        }

        // ---- odd half: tile complete -> bias + scatter-store (fire-and-forget) ----
        if (hf) {
            const float bk = s ? bk2 : bk1;
            const int bimg = bid / 49;
            const int hw0  = (bid % 49) * 16;
            float* __restrict__ outp = out + (s ? (size_t)OUT_STRIDE : 0);
            size_t rbase[4];
            #pragma unroll
            for (int r = 0; r < 4; ++r) {
                int hw = hw0 + lhi * 4 + r;
                int h = hw / 28, w = hw % 28;
                rbase[r] = ((size_t)(bimg * 112 + h * 4) * 112 + (w * 4)) * 64 + kk;
            }
            #pragma unroll
            for (int i = 0; i < 4; ++i)
                #pragma unroll
                for (int j = 0; j < 4; ++j) {
                    #pragma unroll
                    for (int r = 0; r < 4; ++r)
                        outp[rbase[r] + (size_t)((i * 112 + j) * 64)] = o[i][j][r] + bk;
                    o[i][j] = (f32x4){0.f, 0.f, 0.f, 0.f};
                }
        }

        __builtin_amdgcn_s_barrier();   // all waves done reading buf[m&1] before
                                        // iter m+1 issues stage(m+2) into it
    }
}

extern "C" void kernel_launch(void* const* d_in, const int* in_sizes, int n_in,
                              void* d_out, int out_size, void* d_ws, size_t ws_size,
                              hipStream_t stream) {
    const float* t1 = (const float*)d_in[0];
    const float* t2 = (const float*)d_in[1];
    const float* w1 = (const float*)d_in[2];
    const float* w2 = (const float*)d_in[3];
    const float* b1 = (const float*)d_in[4];
    const float* b2 = (const float*)d_in[5];
    unsigned short* wfrag = (unsigned short*)d_ws;   // 256 KB bf16 fragments
    float* out = (float*)d_out;

    repack_weights<<<dim3(512), dim3(256), 0, stream>>>(w1, w2, wfrag);
    iwht_main<<<dim3(GRIDX), dim3(256), 0, stream>>>(t1, t2, wfrag, b1, b2, out);
}

// Round 6
// 197.004 us; speedup vs baseline: 1.0395x; 1.0395x over previous
//
#include <hip/hip_runtime.h>
#include <hip/hip_bf16.h>

typedef float f32x4 __attribute__((ext_vector_type(4)));
typedef short s16x8 __attribute__((ext_vector_type(8)));

#define NPIX       12544      // B*nH*nW = 16*28*28
#define OUT_STRIDE 12845056   // 16*112*112*64 elements per stream output

__device__ __forceinline__ unsigned short f2bf(float x) {
    union { float f; unsigned u; } un; un.f = x;
    unsigned r = un.u + 0x7FFFu + ((un.u >> 16) & 1u);  // RNE
    return (unsigned short)(r >> 16);
}

__device__ __forceinline__ short bfs(float x) {
    __hip_bfloat16 h = __float2bfloat16(x);
    return *reinterpret_cast<short*>(&h);
}

__device__ __forceinline__ void gload_lds16(const void* g, void* l) {
    __builtin_amdgcn_global_load_lds(
        (const __attribute__((address_space(1))) unsigned int*)g,
        (__attribute__((address_space(3))) unsigned int*)l, 16, 0, 0);
}

// Repack weights fp32 -> bf16 MFMA B-fragments in d_ws, scaled by 1/16.
// Fragment (lane,e) = w[t][c = ks*32 + (lane>>4)*8 + e][k = nt*16 + (lane&15)] / 16
// at granule (((s*16+t)*2+ks)*4+nt)*64+lane, element e.
__global__ __launch_bounds__(256) void repack_weights(
        const float* __restrict__ w1, const float* __restrict__ w2,
        unsigned short* __restrict__ wf) {
    int gid = blockIdx.x * 256 + threadIdx.x;   // [s][t][c][k], k fastest
    int k = gid & 63;
    int c = (gid >> 6) & 63;
    int t = (gid >> 12) & 15;
    int s = (gid >> 16) & 1;
    const float* __restrict__ w = s ? w2 : w1;
    float val = w[gid & 65535] * 0.0625f;
    int e = c & 7, lhi = (c >> 3) & 3, ks = c >> 5;
    int l  = lhi * 16 + (k & 15);
    int nt = k >> 4;
    int dst = ((((s * 16 + t) * 2 + ks) * 4 + nt) * 64 + l) * 8 + e;
    wf[dst] = f2bf(val);
}

// One tile (16 pixels x 1 stream) per block; 1568 blocks, HW-balanced.
// In-tile: dbuf halves with counted vmcnt; epilogue = LDS transpose ->
// 16 x 1KB contiguous dwordx4 store runs per wave.
__global__ __launch_bounds__(256, 2) void iwht_main(
        const float* __restrict__ trans1, const float* __restrict__ trans2,
        const unsigned short* __restrict__ wf,
        const float* __restrict__ bias1, const float* __restrict__ bias2,
        float* __restrict__ out) {
    __shared__ __align__(16) unsigned char lds[65536];   // 2 x 32 KB A halves / 64 KB out-stage

    const int tid  = threadIdx.x;
    const int wid  = tid >> 6;
    const int lane = tid & 63;
    const int lrow = lane & 15;
    const int lhi  = lane >> 4;

    const int tau = blockIdx.x;                  // 0..1567
    const int s   = (tau >= 784) ? 1 : 0;
    const int bid = tau - s * 784;
    const float* __restrict__ trans = s ? trans2 : trans1;
    const int   kk = wid * 16 + lrow;            // this wave's k (C/D col = lane&15)
    const float bk = (s ? bias2 : bias1)[kk];

    // per-lane pre-swizzled staging source (wave wid stages granule q=wid)
    const int qsrc = (wid >> 1) * 32 + lhi * 8 + (wid & 1) * 4;
    const float* __restrict__ g0 = trans + (size_t)(bid * 16 + lrow) * 64 + qsrc;

    // ---- stage half0 (t=0..7) -> lds[0,32K) ----
    #pragma unroll
    for (int tt = 0; tt < 8; ++tt)
        gload_lds16(g0 + (size_t)tt * (NPIX * 64), lds + wid * 1024 + tt * 4096);

    // ---- B(half0) -> bE (issued before stage half1 so vmcnt(8) covers it) ----
    const s16x8* __restrict__ wb = (const s16x8*)wf + (size_t)s * 8192 + wid * 64 + lane;
    s16x8 bE[16];
    #pragma unroll
    for (int tt = 0; tt < 8; ++tt) {
        bE[tt * 2 + 0] = wb[(size_t)(tt * 2 + 0) * 256];
        bE[tt * 2 + 1] = wb[(size_t)(tt * 2 + 1) * 256];
    }

    // ---- stage half1 (t=8..15) -> lds[32K,64K) ----
    #pragma unroll
    for (int tt = 0; tt < 8; ++tt)
        gload_lds16(g0 + (size_t)(8 + tt) * (NPIX * 64),
                    lds + 32768 + wid * 1024 + tt * 4096);

    asm volatile("s_waitcnt vmcnt(8)" ::: "memory");   // half0 + bE landed; half1 in flight
    __builtin_amdgcn_sched_barrier(0);
    __builtin_amdgcn_s_barrier();

    // ---- B(half1) -> bO (lands under compute0) ----
    s16x8 bO[16];
    #pragma unroll
    for (int tt = 0; tt < 8; ++tt) {
        bO[tt * 2 + 0] = wb[(size_t)((8 + tt) * 2 + 0) * 256];
        bO[tt * 2 + 1] = wb[(size_t)((8 + tt) * 2 + 1) * 256];
    }

    f32x4 o[4][4];
    #pragma unroll
    for (int i = 0; i < 4; ++i)
        #pragma unroll
        for (int j = 0; j < 4; ++j)
            o[i][j] = (f32x4){0.f, 0.f, 0.f, 0.f};

    // compute one half: u-groups {ubase, ubase+1} from hb with B-set bb
    auto compute_half = [&](const unsigned char* hb, const s16x8 (&bb)[16], int ubase) {
        #pragma unroll
        for (int g = 0; g < 2; ++g) {
            f32x4 acc[4];
            #pragma unroll
            for (int v = 0; v < 4; ++v) {
                const int tt = g * 4 + v;
                const unsigned char* ab = hb + tt * 4096 + lane * 16;
                f32x4 q0 = *(const f32x4*)(ab);
                f32x4 q1 = *(const f32x4*)(ab + 1024);
                f32x4 q2 = *(const f32x4*)(ab + 2048);
                f32x4 q3 = *(const f32x4*)(ab + 3072);
                s16x8 a0, a1;
                #pragma unroll
                for (int e = 0; e < 4; ++e) {
                    a0[e] = bfs(q0[e]); a0[4 + e] = bfs(q1[e]);
                    a1[e] = bfs(q2[e]); a1[4 + e] = bfs(q3[e]);
                }
                f32x4 tacc = {0.f, 0.f, 0.f, 0.f};
                tacc = __builtin_amdgcn_mfma_f32_16x16x32_bf16(a0, bb[tt * 2 + 0], tacc, 0, 0, 0);
                tacc = __builtin_amdgcn_mfma_f32_16x16x32_bf16(a1, bb[tt * 2 + 1], tacc, 0, 0, 0);
                acc[v] = tacc;
            }
            f32x4 e0 = acc[0] + acc[1], e1 = acc[0] - acc[1];
            f32x4 e2 = acc[2] + acc[3], e3 = acc[2] - acc[3];
            f32x4 g0v = e0 + e2, g1v = e1 + e3, g2v = e0 - e2, g3v = e1 - e3;
            const int u = ubase + g;
            const float s1 = (u & 1) ? -1.f : 1.f;
            const float s2 = (u & 2) ? -1.f : 1.f;
            const float s3 = s1 * s2;
            #pragma unroll
            for (int j = 0; j < 4; ++j) {
                f32x4 gj = (j == 0) ? g0v : ((j == 1) ? g1v : ((j == 2) ? g2v : g3v));
                o[0][j] += gj;
                o[1][j] += s1 * gj;
                o[2][j] += s2 * gj;
                o[3][j] += s3 * gj;
            }
        }
    };

    compute_half(lds, bE, 0);

    asm volatile("s_waitcnt vmcnt(0)" ::: "memory");   // half1 + bO landed
    __builtin_amdgcn_sched_barrier(0);
    __builtin_amdgcn_s_barrier();

    compute_half(lds + 32768, bO, 2);

    // ---- epilogue: transpose via LDS -> contiguous 1 KB store runs ----
    __builtin_amdgcn_s_barrier();                  // all waves done reading LDS
    // region i (16 KB): [pixel p][j][k] floats; byte-in-chunk XOR-swizzled by p&7
    #pragma unroll
    for (int i = 0; i < 4; ++i)
        #pragma unroll
        for (int r = 0; r < 4; ++r) {
            const int p = lhi * 4 + r;
            unsigned char* base = lds + i * 16384 + p * 1024;
            const int swz = (p & 7) << 4;
            #pragma unroll
            for (int j = 0; j < 4; ++j)
                *(float*)(base + ((j * 256 + kk * 4) ^ swz)) = o[i][j][r] + bk;
        }
    asm volatile("s_waitcnt lgkmcnt(0)" ::: "memory");
    __builtin_amdgcn_sched_barrier(0);
    __builtin_amdgcn_s_barrier();

    const int bimg = bid / 49;
    const int hw0  = (bid % 49) * 16;
    float* __restrict__ outp = out + (s ? (size_t)OUT_STRIDE : 0);
    #pragma unroll
    for (int n = 0; n < 16; ++n) {                 // wave wid stores row i=wid, pixel n
        f32x4 v = *(const f32x4*)(lds + wid * 16384 + n * 1024
                                  + ((lane * 16) ^ ((n & 7) << 4)));
        const int hw = hw0 + n;
        const int h = hw / 28, w = hw % 28;
        *(f32x4*)(outp + ((size_t)(bimg * 112 + h * 4 + wid) * 112 + w * 4) * 64
                  + lane * 4) = v;                 // 1 KB contiguous per wave-instr
    }
}

extern "C" void kernel_launch(void* const* d_in, const int* in_sizes, int n_in,
                              void* d_out, int out_size, void* d_ws, size_t ws_size,
                              hipStream_t stream) {
    const float* t1 = (const float*)d_in[0];
    const float* t2 = (const float*)d_in[1];
    const float* w1 = (const float*)d_in[2];
    const float* w2 = (const float*)d_in[3];
    const float* b1 = (const float*)d_in[4];
    const float* b2 = (const float*)d_in[5];
    unsigned short* wfrag = (unsigned short*)d_ws;   // 256 KB bf16 fragments
    float* out = (float*)d_out;

    repack_weights<<<dim3(512), dim3(256), 0, stream>>>(w1, w2, wfrag);
    iwht_main<<<dim3(1568), dim3(256), 0, stream>>>(t1, t2, wfrag, b1, b2, out);
}